// Round 8
// baseline (874.859 us; speedup 1.0000x reference)
//
#include <hip/hip_runtime.h>
#include <math.h>

#define BB 4
#define QQ 75
#define CC 640
#define HW 100
#define NWAY 5
#define KSHOT 5
#define MS 500
#define MSP 512
#define MTOT 7500
#define MPAD 7680     // 60 tiles of 128
#define TEMPER 2.0f
#define EPSN 1e-8f
#define NCH 8         // n-chunks of 64 per way

typedef _Float16 v8h __attribute__((ext_vector_type(8)));
typedef float v4f __attribute__((ext_vector_type(4)));

__device__ inline void splitv(const float* x, v8h& hi, v8h& lo) {
#pragma unroll
    for (int j = 0; j < 8; ++j) {
        _Float16 h = (_Float16)x[j];
        float r0 = x[j] - (float)h;
        hi[j] = h; lo[j] = (_Float16)r0;
    }
}

// ---------------- norms: inverse channel-norms, query (300) + support (100) -----
// Also zeroes out[0] (accumulated by finalize's atomicAdd).
__global__ __launch_bounds__(128) void norms(const float* __restrict__ qx,
                                             const float* __restrict__ sup,
                                             float* __restrict__ invq,
                                             float* __restrict__ invs,
                                             float* __restrict__ out) {
    int bid = blockIdx.x, t = threadIdx.x;
    if (bid == 0 && t == 0) out[0] = 0.f;
    const float* src; float* dst;
    if (bid < BB * QQ) { src = qx + (size_t)bid * CC * HW; dst = invq + bid * HW; }
    else { int bs = bid - BB * QQ; src = sup + (size_t)bs * CC * HW; dst = invs + bs * HW; }
    if (t < HW) {
        float ss = 0.f;
        for (int c = 0; c < CC; ++c) { float v = src[c * HW + t]; ss += v * v; }
        dst[t] = 1.f / (sqrtf(ss) + EPSN);
    }
}

// ---------------- prep_AB: transpose+split one 64-channel chunk per block --------
// g < 3000: A (bq, ct) raw query -> Ahi/Alo (b, m, c) f16 k-contiguous
// g >= 3000: B (bs, ct) normalized support -> Bhi/Blo (bw, n, c)
__global__ __launch_bounds__(256) void prep_AB(const float* __restrict__ qx,
                                               const float* __restrict__ sup,
                                               const float* __restrict__ invs,
                                               _Float16* __restrict__ Ahi,
                                               _Float16* __restrict__ Alo,
                                               _Float16* __restrict__ Bhi,
                                               _Float16* __restrict__ Blo) {
    int g = blockIdx.x;
    const float* src; const float* inv = 0;
    _Float16 *dh, *dl;
    int ct;
    if (g < BB * QQ * 10) {
        int bq = g / 10; ct = g % 10;
        int b = bq / QQ, qi = bq % QQ;
        src = qx + ((size_t)bq * CC + ct * 64) * HW;
        size_t rowbase = (size_t)b * MPAD + qi * HW;
        dh = Ahi + rowbase * CC; dl = Alo + rowbase * CC;
    } else {
        int h = g - BB * QQ * 10;
        int bs = h / 10; ct = h % 10;
        int b = bs / 25, s = bs % 25, w = s / KSHOT, shot = s % KSHOT;
        src = sup + ((size_t)bs * CC + ct * 64) * HW;
        size_t rowbase = (size_t)(b * NWAY + w) * MSP + shot * HW;
        dh = Bhi + rowbase * CC; dl = Blo + rowbase * CC;
        inv = invs + bs * HW;
    }
    __shared__ float tile[64 * 101];   // padded stride 101: transpose reads 2-way max
    __shared__ float invt[HW];
    int t = threadIdx.x;
    if (t < HW) invt[t] = inv ? inv[t] : 1.f;
    // vectorized load: 1600 float4 (HW%4==0 so each float4 stays in one row)
    for (int v = t; v < 1600; v += 256) {
        float4 x = ((const float4*)src)[v];
        int row = v / 25, col = (v % 25) * 4;
        float* d = &tile[row * 101 + col];
        d[0] = x.x; d[1] = x.y; d[2] = x.z; d[3] = x.w;
    }
    __syncthreads();
    for (int cell = t; cell < 800; cell += 256) {
        int p = cell >> 3, oct = cell & 7;
        float iv = invt[p];
        float x[8];
#pragma unroll
        for (int j = 0; j < 8; ++j) x[j] = tile[(oct * 8 + j) * 101 + p] * iv;
        v8h hi, lo; splitv(x, hi, lo);
        size_t off = (size_t)p * CC + ct * 64 + oct * 8;
        *(v8h*)(dh + off) = hi;
        *(v8h*)(dl + off) = lo;
    }
}

// ---------------- simkernel: NO-LDS direct-from-global fp16x3 MFMA ---------------
// Grid: bid = ((b*20 + nt)*60 + mt). nt: way w=nt>>2, n0w=(nt&3)*128.
// 4 waves of 64m x 64n (4x4 16x16x32 frags). Fragments loaded straight from the
// k-contiguous prepped arrays (A-layout: row=lane&15, k-oct=lane>>4 -> 16B/lane).
// No __shared__, no barriers -> no vmcnt(0) drain; waves pipeline freely,
// reuse served by L1/L2/L3 (whole prepped set = 105 MB < L3).
__global__ __launch_bounds__(256) void simkernel(
        const _Float16* __restrict__ Ahi, const _Float16* __restrict__ Alo,
        const _Float16* __restrict__ Bhi, const _Float16* __restrict__ Blo,
        float* __restrict__ pmax, unsigned short* __restrict__ pidx) {
    int bid = blockIdx.x;
    int mt = bid % 60; int t2 = bid / 60;
    int nt = t2 % 20;  int b = t2 / 20;
    int m0 = mt * 128;
    int w = nt >> 2, n0w = (nt & 3) * 128;

    int tid = threadIdx.x;
    int lane = tid & 63;
    int wv = tid >> 6;
    int mrow_w = (wv >> 1) * 64;
    int ncol_w = (wv & 1) * 64;
    int lq = lane >> 4, lc = lane & 15;

    const _Float16* baseAh = Ahi + ((size_t)b * MPAD + m0 + mrow_w) * CC;
    const _Float16* baseAl = Alo + ((size_t)b * MPAD + m0 + mrow_w) * CC;
    const _Float16* baseBh = Bhi + ((size_t)(b * NWAY + w) * MSP + n0w + ncol_w) * CC;
    const _Float16* baseBl = Blo + ((size_t)(b * NWAY + w) * MSP + n0w + ncol_w) * CC;

    int offF[4];
#pragma unroll
    for (int f = 0; f < 4; ++f) offF[f] = (f * 16 + lc) * CC + lq * 8;

    v4f acc[4][4];
#pragma unroll
    for (int mf = 0; mf < 4; ++mf)
#pragma unroll
        for (int nf = 0; nf < 4; ++nf) acc[mf][nf] = (v4f)0.f;

#pragma unroll 2
    for (int ch = 0; ch < 20; ++ch) {
        int ko = ch * 32;
        v8h ah[4], al[4], bh[4], bl[4];
#pragma unroll
        for (int f = 0; f < 4; ++f) {
            ah[f] = *(const v8h*)(baseAh + offF[f] + ko);
            al[f] = *(const v8h*)(baseAl + offF[f] + ko);
            bh[f] = *(const v8h*)(baseBh + offF[f] + ko);
            bl[f] = *(const v8h*)(baseBl + offF[f] + ko);
        }
#pragma unroll
        for (int nf = 0; nf < 4; ++nf) {
#pragma unroll
            for (int mf = 0; mf < 4; ++mf) {
                acc[mf][nf] = __builtin_amdgcn_mfma_f32_16x16x32_f16(ah[mf], bh[nf], acc[mf][nf], 0, 0, 0);
                acc[mf][nf] = __builtin_amdgcn_mfma_f32_16x16x32_f16(ah[mf], bl[nf], acc[mf][nf], 0, 0, 0);
                acc[mf][nf] = __builtin_amdgcn_mfma_f32_16x16x32_f16(al[mf], bh[nf], acc[mf][nf], 0, 0, 0);
            }
        }
    }

    int chunk = (nt & 3) * 2 + (wv & 1);        // 64-col chunk index, ascending n
#pragma unroll
    for (int mf = 0; mf < 4; ++mf) {
#pragma unroll
        for (int r = 0; r < 4; ++r) {
            float v = -__builtin_inff(); int idx = 0x7fffffff;
#pragma unroll
            for (int nf = 0; nf < 4; ++nf) {
                int n_way = n0w + ncol_w + nf * 16 + lc;
                float cv = acc[mf][nf][r];
                if (n_way < MS && cv > v) { v = cv; idx = n_way; }
            }
#pragma unroll
            for (int msk = 1; msk < 16; msk <<= 1) {
                float ov = __shfl_xor(v, msk);
                int oi = __shfl_xor(idx, msk);
                if (ov > v || (ov == v && oi < idx)) { v = ov; idx = oi; }
            }
            if (lc == 0) {
                int mrow = m0 + mrow_w + mf * 16 + lq * 4 + r;
                size_t o = ((size_t)(b * NWAY + w) * NCH + chunk) * MPAD + mrow;
                pmax[o] = v;
                pidx[o] = (unsigned short)(idx & 0xffff);
            }
        }
    }
}

// ================= FALLBACK PATH (ws too small) =================
__global__ void norm_support(const float* __restrict__ sup, float* __restrict__ snre) {
    int bid = blockIdx.x;
    int b = bid / 25, s = bid % 25;
    int w = s / KSHOT, shot = s % KSHOT;
    const float* src = sup + (size_t)bid * CC * HW;
    float* dst = snre + ((size_t)(b * NWAY + w)) * CC * MSP + shot * HW;
    __shared__ float inv[HW];
    int t = threadIdx.x;
    if (t < HW) {
        float ss = 0.f;
        for (int c = 0; c < CC; ++c) { float v = src[c * HW + t]; ss += v * v; }
        inv[t] = 1.f / (sqrtf(ss) + EPSN);
    }
    __syncthreads();
    for (int i = t; i < CC * HW; i += 256) {
        int c = i / HW, p = i % HW;
        dst[c * MSP + p] = src[i] * inv[p];
    }
    if (shot == KSHOT - 1) {
        float* padbase = snre + ((size_t)(b * NWAY + w)) * CC * MSP;
        for (int i = t; i < CC * (MSP - MS); i += 256) {
            int c = i / (MSP - MS), j = i % (MSP - MS);
            padbase[c * MSP + MS + j] = 0.f;
        }
    }
}

__global__ __launch_bounds__(256) void simkernel_fb(
        const float* __restrict__ qx, const float* __restrict__ snre,
        float* __restrict__ pmax, unsigned short* __restrict__ pidx) {
    __shared__ char lds_fb[49152];
    v8h* AHI = (v8h*)(lds_fb);
    v8h* ALO = (v8h*)(lds_fb + 8192);
    v8h* BHI = (v8h*)(lds_fb + 16384);
    v8h* BLO = (v8h*)(lds_fb + 32768);

    int bid = blockIdx.x;
    int mt = bid % 60; int t2 = bid / 60;
    int nt = t2 % 10;  int b = t2 / 10;
    int m0 = mt * 128;
    int w = nt >> 1;
    int n0w = (nt & 1) * 256;

    int tid = threadIdx.x;
    const float* Abase = qx + (size_t)b * QQ * CC * HW;
    const float* Bbase = snre + (size_t)(b * NWAY + w) * CC * MSP;

    int oct = tid & 3;
    int arow = tid >> 2;
    int aqi[2], ap[2];
#pragma unroll
    for (int pass = 0; pass < 2; ++pass) {
        int mg = m0 + arow + pass * 64;
        if (mg >= MTOT) mg = 0;
        aqi[pass] = mg / HW; ap[pass] = mg % HW;
    }

    v4f acc[4][8];
#pragma unroll
    for (int mf = 0; mf < 4; ++mf)
#pragma unroll
        for (int nf = 0; nf < 8; ++nf) acc[mf][nf] = (v4f)0.f;

    int lane = tid & 63;
    int wv = tid >> 6;
    int mrow_w = (wv >> 1) * 64;
    int ncol_w = (wv & 1) * 128;
    int lq = lane >> 4, lc = lane & 15;

    for (int ch = 0; ch < 20; ++ch) {
        int c0 = ch * 32 + oct * 8;
        __syncthreads();
#pragma unroll
        for (int pass = 0; pass < 2; ++pass) {
            const float* src = Abase + ((size_t)aqi[pass] * CC + c0) * HW + ap[pass];
            float x[8];
#pragma unroll
            for (int j = 0; j < 8; ++j) x[j] = src[j * HW];
            v8h hi, lo; splitv(x, hi, lo);
            int cell = (arow + pass * 64) * 4 + oct;
            AHI[cell] = hi; ALO[cell] = lo;
        }
#pragma unroll
        for (int pass = 0; pass < 4; ++pass) {
            int nrow = arow + pass * 64;
            const float* src = Bbase + (size_t)c0 * MSP + n0w + nrow;
            float x[8];
#pragma unroll
            for (int j = 0; j < 8; ++j) x[j] = src[j * MSP];
            v8h hi, lo; splitv(x, hi, lo);
            int cell = nrow * 4 + oct;
            BHI[cell] = hi; BLO[cell] = lo;
        }
        __syncthreads();

        v8h ahi[4], alo[4];
#pragma unroll
        for (int mf = 0; mf < 4; ++mf) {
            int idx = (mrow_w + mf * 16 + lc) * 4 + lq;
            ahi[mf] = AHI[idx]; alo[mf] = ALO[idx];
        }
#pragma unroll
        for (int nf = 0; nf < 8; ++nf) {
            int idx = (ncol_w + nf * 16 + lc) * 4 + lq;
            v8h bhi = BHI[idx], blo = BLO[idx];
#pragma unroll
            for (int mf = 0; mf < 4; ++mf) {
                acc[mf][nf] = __builtin_amdgcn_mfma_f32_16x16x32_f16(ahi[mf], bhi, acc[mf][nf], 0, 0, 0);
                acc[mf][nf] = __builtin_amdgcn_mfma_f32_16x16x32_f16(ahi[mf], blo, acc[mf][nf], 0, 0, 0);
                acc[mf][nf] = __builtin_amdgcn_mfma_f32_16x16x32_f16(alo[mf], bhi, acc[mf][nf], 0, 0, 0);
            }
        }
    }

    int chunkidx = (nt & 1) * 2 + (wv & 1);   // 128-col chunk of the way
#pragma unroll
    for (int mf = 0; mf < 4; ++mf) {
#pragma unroll
        for (int r = 0; r < 4; ++r) {
            float v = -__builtin_inff(); int idx = 0x7fffffff;
#pragma unroll
            for (int nf = 0; nf < 8; ++nf) {
                int n_way = n0w + ncol_w + nf * 16 + lc;
                float cv = acc[mf][nf][r];
                if (n_way < MS && cv > v) { v = cv; idx = n_way; }
            }
#pragma unroll
            for (int msk = 1; msk < 16; msk <<= 1) {
                float ov = __shfl_xor(v, msk);
                int oi = __shfl_xor(idx, msk);
                if (ov > v || (ov == v && oi < idx)) { v = ov; idx = oi; }
            }
            if (lc == 0) {
                int mrow = m0 + mrow_w + mf * 16 + lq * 4 + r;
                size_t ob = (size_t)(b * NWAY + w) * NCH * MPAD + mrow;
                int s_hi = (idx != 0x7fffffff) ? (idx >> 6) : -1;  // 64-col slot
#pragma unroll
                for (int sl2 = 0; sl2 < 2; ++sl2) {
                    int sl = chunkidx * 2 + sl2;
                    if (sl == s_hi) {
                        pmax[ob + (size_t)sl * MPAD] = v;
                        pidx[ob + (size_t)sl * MPAD] = (unsigned short)(idx & 0xffff);
                    } else {
                        pmax[ob + (size_t)sl * MPAD] = -__builtin_inff();
                        pidx[ob + (size_t)sl * MPAD] = 0xffffu;
                    }
                }
            }
        }
    }
}

// ------- finalize: combine chunks + top-2 diff + mutual mask + predict + NLL -----
__global__ __launch_bounds__(128) void finalize(
        const float* __restrict__ pmax, const unsigned short* __restrict__ pidx,
        const float* __restrict__ invq, const int* __restrict__ qy,
        float* __restrict__ out) {
    int bq = blockIdx.x;
    int b = bq / QQ, qi = bq % QQ;
    __shared__ float sm[NWAY][HW];
    __shared__ int   si[NWAY][HW];
    __shared__ float diffv[HW];
    __shared__ int   nearest[HW];
    __shared__ float maskv[HW];
    __shared__ float pred[NWAY];
    int t = threadIdx.x;
    if (t < HW) {
        float iq = invq[bq * HW + t];
        for (int w = 0; w < NWAY; ++w) {
            size_t base = ((size_t)(b * NWAY + w) * NCH) * MPAD + qi * HW + t;
            float best = -__builtin_inff(); int bi = 0x7fffffff;
            for (int c = 0; c < NCH; ++c) {
                float v = pmax[base + (size_t)c * MPAD];
                if (v > best) { best = v; bi = pidx[base + (size_t)c * MPAD]; }
            }
            sm[w][t] = best * iq;
            si[w][t] = bi;
        }
    }
    __syncthreads();
    if (t < HW) {
        float v1 = -INFINITY, v2 = -INFINITY;
        float bestv = -INFINITY; int bestslot = 0;
        for (int w = 0; w < NWAY; ++w) {
            float v = sm[w][t];
            if (v > v1) { v2 = v1; v1 = v; } else if (v > v2) { v2 = v; }
            if (v > bestv) { bestv = v; bestslot = w * MS + si[w][t]; }
        }
        diffv[t] = v1 - v2;
        nearest[t] = bestslot;
    }
    __syncthreads();
    if (t < HW) {
        int slot = nearest[t];
        float bv = (nearest[0] == slot) ? diffv[0] : 0.f;
        int bm = 0;
        for (int m = 1; m < HW; ++m) {
            float val = (nearest[m] == slot) ? diffv[m] : 0.f;
            if (val > bv) { bv = val; bm = m; }
        }
        maskv[t] = (bm == t) ? TEMPER : 0.f;
    }
    __syncthreads();
    if (t < NWAY) {
        float s = 0.f;
        for (int m = 0; m < HW; ++m) s += sm[t][m] * maskv[m];
        pred[t] = s;
    }
    __syncthreads();
    if (t == 0) {
        float mx = pred[0];
        for (int w = 1; w < NWAY; ++w) mx = fmaxf(mx, pred[w]);
        float se = 0.f;
        for (int w = 0; w < NWAY; ++w) se += expf(pred[w] - mx);
        float lse = mx + logf(se);
        int y = qy[bq];
        atomicAdd(out, -(pred[y] - lse) * (1.f / (BB * QQ)));
    }
}

extern "C" void kernel_launch(void* const* d_in, const int* in_sizes, int n_in,
                              void* d_out, int out_size, void* d_ws, size_t ws_size,
                              hipStream_t stream) {
    const float* sup = (const float*)d_in[0];   // support_xf (4,25,640,10,10) f32
    const float* qx  = (const float*)d_in[2];   // query_xf   (4,75,640,10,10) f32
    const int*   qy  = (const int*)d_in[3];     // query_y    (4,75) int32
    float* out = (float*)d_out;

    // header region (~7.5 MB)
    size_t pcount = (size_t)BB * NWAY * NCH * MPAD;     // 1,228,800
    float* pmax = (float*)d_ws;
    unsigned short* pidx = (unsigned short*)(pmax + pcount);
    float* invq = (float*)(pidx + pcount);
    float* invs = invq + (size_t)BB * MTOT;
    char*  big = (char*)(invs + (size_t)BB * 25 * HW);
    size_t header = (size_t)(big - (char*)d_ws);
    size_t needA = (size_t)BB * MPAD * CC * 2;          // 39.3 MB per array
    size_t needB = (size_t)BB * NWAY * MSP * CC * 2;    // 13.1 MB per array
    size_t need_fast = header + 2 * (needA + needB);

    hipLaunchKernelGGL(norms, dim3(BB * QQ + BB * 25), dim3(128), 0, stream,
                       qx, sup, invq, invs, out);

    if (ws_size >= need_fast) {
        _Float16* Ahi = (_Float16*)big;
        _Float16* Alo = Ahi + (size_t)BB * MPAD * CC;
        _Float16* Bhi = Alo + (size_t)BB * MPAD * CC;
        _Float16* Blo = Bhi + (size_t)BB * NWAY * MSP * CC;
        hipLaunchKernelGGL(prep_AB, dim3(BB * QQ * 10 + BB * 25 * 10), dim3(256), 0, stream,
                           qx, sup, invs, Ahi, Alo, Bhi, Blo);
        hipLaunchKernelGGL(simkernel, dim3(BB * 20 * 60), dim3(256), 0, stream,
                           Ahi, Alo, Bhi, Blo, pmax, pidx);
    } else {
        float* snre = (float*)big;   // 26.2 MB
        hipLaunchKernelGGL(norm_support, dim3(BB * 25), dim3(256), 0, stream, sup, snre);
        hipLaunchKernelGGL(simkernel_fb, dim3(BB * 10 * 60), dim3(256), 0, stream,
                           qx, snre, pmax, pidx);
    }
    hipLaunchKernelGGL(finalize, dim3(BB * QQ), dim3(128), 0, stream,
                       pmax, pidx, invq, qy, out);
}

// Round 9
// 618.168 us; speedup vs baseline: 1.4152x; 1.4152x over previous
//
#include <hip/hip_runtime.h>
#include <math.h>

#define BB 4
#define QQ 75
#define CC 640
#define HW 100
#define NWAY 5
#define KSHOT 5
#define MS 500
#define MSP 512
#define MTOT 7500
#define MPAD 7680     // 60 tiles of 128
#define TEMPER 2.0f
#define EPSN 1e-8f
#define NCH 8         // n-chunks of 64 per way
#define LBA 16384     // one A LDS buffer: hi 8 KB + lo 8 KB

typedef _Float16 v8h __attribute__((ext_vector_type(8)));
typedef float v4f __attribute__((ext_vector_type(4)));

__device__ inline void splitv(const float* x, v8h& hi, v8h& lo) {
#pragma unroll
    for (int j = 0; j < 8; ++j) {
        _Float16 h = (_Float16)x[j];
        float r0 = x[j] - (float)h;
        hi[j] = h; lo[j] = (_Float16)r0;
    }
}

typedef __attribute__((address_space(3))) unsigned int lds_uint;
typedef __attribute__((address_space(1))) const unsigned int glb_uint;
__device__ inline void gl_lds16(const void* g, void* l) {
    __builtin_amdgcn_global_load_lds((glb_uint*)g, (lds_uint*)l, 16, 0, 0);
}

// ---------------- norms: inverse channel-norms, query (300) + support (100) -----
__global__ __launch_bounds__(128) void norms(const float* __restrict__ qx,
                                             const float* __restrict__ sup,
                                             float* __restrict__ invq,
                                             float* __restrict__ invs,
                                             float* __restrict__ out) {
    int bid = blockIdx.x, t = threadIdx.x;
    if (bid == 0 && t == 0) out[0] = 0.f;
    const float* src; float* dst;
    if (bid < BB * QQ) { src = qx + (size_t)bid * CC * HW; dst = invq + bid * HW; }
    else { int bs = bid - BB * QQ; src = sup + (size_t)bs * CC * HW; dst = invs + bs * HW; }
    if (t < HW) {
        float ss = 0.f;
        for (int c = 0; c < CC; ++c) { float v = src[c * HW + t]; ss += v * v; }
        dst[t] = 1.f / (sqrtf(ss) + EPSN);
    }
}

// ---------------- prep_AB: transpose+split one 64-channel chunk per block --------
__global__ __launch_bounds__(256) void prep_AB(const float* __restrict__ qx,
                                               const float* __restrict__ sup,
                                               const float* __restrict__ invs,
                                               _Float16* __restrict__ Ahi,
                                               _Float16* __restrict__ Alo,
                                               _Float16* __restrict__ Bhi,
                                               _Float16* __restrict__ Blo) {
    int g = blockIdx.x;
    const float* src; const float* inv = 0;
    _Float16 *dh, *dl;
    int ct;
    if (g < BB * QQ * 10) {
        int bq = g / 10; ct = g % 10;
        int b = bq / QQ, qi = bq % QQ;
        src = qx + ((size_t)bq * CC + ct * 64) * HW;
        size_t rowbase = (size_t)b * MPAD + qi * HW;
        dh = Ahi + rowbase * CC; dl = Alo + rowbase * CC;
    } else {
        int h = g - BB * QQ * 10;
        int bs = h / 10; ct = h % 10;
        int b = bs / 25, s = bs % 25, w = s / KSHOT, shot = s % KSHOT;
        src = sup + ((size_t)bs * CC + ct * 64) * HW;
        size_t rowbase = (size_t)(b * NWAY + w) * MSP + shot * HW;
        dh = Bhi + rowbase * CC; dl = Blo + rowbase * CC;
        inv = invs + bs * HW;
    }
    __shared__ float tile[64 * 101];   // padded stride 101
    __shared__ float invt[HW];
    int t = threadIdx.x;
    if (t < HW) invt[t] = inv ? inv[t] : 1.f;
    for (int v = t; v < 1600; v += 256) {
        float4 x = ((const float4*)src)[v];
        int row = v / 25, col = (v % 25) * 4;
        float* d = &tile[row * 101 + col];
        d[0] = x.x; d[1] = x.y; d[2] = x.z; d[3] = x.w;
    }
    __syncthreads();
    for (int cell = t; cell < 800; cell += 256) {
        int p = cell >> 3, oct = cell & 7;
        float iv = invt[p];
        float x[8];
#pragma unroll
        for (int j = 0; j < 8; ++j) x[j] = tile[(oct * 8 + j) * 101 + p] * iv;
        v8h hi, lo; splitv(x, hi, lo);
        size_t off = (size_t)p * CC + ct * 64 + oct * 8;
        *(v8h*)(dh + off) = hi;
        *(v8h*)(dl + off) = lo;
    }
}

// ---------------- simkernel: A in dbuf LDS (DMA), B direct-global prefetch -------
// Grid: bid = ((b*20 + nt)*60 + mt). nt: way w=nt>>2, n0w=(nt&3)*128.
// Block 128m x 128n, 4 waves of 64x64 (4x4 16x16x32 frags), fp16x3 split.
// LDS holds only A (hi/lo), 2 x 16 KB double-buffered -> 2 blocks/CU.
// B fragments loaded straight from k-contiguous global, one chunk ahead into
// registers; the barrier vmcnt(0) drain then finds all loads already landed.
__global__ __launch_bounds__(256, 2) void simkernel(
        const _Float16* __restrict__ Ahi, const _Float16* __restrict__ Alo,
        const _Float16* __restrict__ Bhi, const _Float16* __restrict__ Blo,
        float* __restrict__ pmax, unsigned short* __restrict__ pidx) {
    __shared__ char lds_raw[2 * LBA];

    int bid = blockIdx.x;
    int mt = bid % 60; int t2 = bid / 60;
    int nt = t2 % 20;  int b = t2 / 20;
    int m0 = mt * 128;
    int w = nt >> 2, n0w = (nt & 3) * 128;

    int tid = threadIdx.x;
    int lane = tid & 63;
    int wvu = __builtin_amdgcn_readfirstlane(tid >> 6);

    const char* baseAh = (const char*)(Ahi + ((size_t)b * MPAD + m0) * CC);
    const char* baseAl = (const char*)(Alo + ((size_t)b * MPAD + m0) * CC);

    // per-lane DMA gather: row r=lane>>2 within 16-row segment, swizzled octet
    int rr0 = lane >> 2;
    int oct = (lane & 3) ^ ((lane >> 3) & 3);
    int laneoff = rr0 * (CC * 2) + oct * 16;

    const char* segsrc[4];
    int segoff[4];
#pragma unroll
    for (int s = 0; s < 4; ++s) {
        int g = wvu * 4 + s;            // 0..15: g<8 Ahi rows g*16, g>=8 Alo
        const char* base = (g < 8) ? baseAh : baseAl;
        segsrc[s] = base + (size_t)((g & 7) * 16) * (CC * 2) + laneoff;
        segoff[s] = g * 1024;
    }

    int wv = tid >> 6;
    int mrow_w = (wv >> 1) * 64;
    int ncol_w = (wv & 1) * 64;
    int lq = lane >> 4, lc = lane & 15;

    int idxA[4];
#pragma unroll
    for (int mf = 0; mf < 4; ++mf) {
        int row = mrow_w + mf * 16 + lc;
        idxA[mf] = row * 4 + (lq ^ ((row >> 1) & 3));
    }

    const _Float16* bBh = Bhi + ((size_t)(b * NWAY + w) * MSP + n0w) * CC;
    const _Float16* bBl = Blo + ((size_t)(b * NWAY + w) * MSP + n0w) * CC;
    int offB[4];
#pragma unroll
    for (int nf = 0; nf < 4; ++nf) offB[nf] = (ncol_w + nf * 16 + lc) * CC + lq * 8;

    v4f acc[4][4];
#pragma unroll
    for (int mf = 0; mf < 4; ++mf)
#pragma unroll
        for (int nf = 0; nf < 4; ++nf) acc[mf][nf] = (v4f)0.f;

    // prologue: DMA A(0) into half 0; load B(0) into regs
#pragma unroll
    for (int s = 0; s < 4; ++s)
        gl_lds16(segsrc[s], lds_raw + segoff[s]);
    v8h bh[4], bl[4];
#pragma unroll
    for (int nf = 0; nf < 4; ++nf) {
        bh[nf] = *(const v8h*)(bBh + offB[nf]);
        bl[nf] = *(const v8h*)(bBl + offB[nf]);
    }

    for (int ch = 0; ch < 20; ++ch) {
        __syncthreads();              // A(ch) in LDS + B(ch) in regs (vmcnt drain)
        if (ch < 19) {                // prefetch A(ch+1) into the other half
            int choff = (ch + 1) * 64;
            int dbase = ((ch + 1) & 1) * LBA;
#pragma unroll
            for (int s = 0; s < 4; ++s)
                gl_lds16(segsrc[s] + choff, lds_raw + dbase + segoff[s]);
        }
        int ko2 = (ch < 19) ? (ch + 1) * 32 : 0;    // B(ch+1) register prefetch
        v8h bh2[4], bl2[4];
#pragma unroll
        for (int nf = 0; nf < 4; ++nf) {
            bh2[nf] = *(const v8h*)(bBh + offB[nf] + ko2);
            bl2[nf] = *(const v8h*)(bBl + offB[nf] + ko2);
        }

        char* cbuf = lds_raw + (ch & 1) * LBA;
        v8h* AH = (v8h*)cbuf;
        v8h* AL = (v8h*)(cbuf + 8192);
        v8h ah[4], al[4];
#pragma unroll
        for (int mf = 0; mf < 4; ++mf) { ah[mf] = AH[idxA[mf]]; al[mf] = AL[idxA[mf]]; }
#pragma unroll
        for (int nf = 0; nf < 4; ++nf) {
#pragma unroll
            for (int mf = 0; mf < 4; ++mf) {
                acc[mf][nf] = __builtin_amdgcn_mfma_f32_16x16x32_f16(ah[mf], bh[nf], acc[mf][nf], 0, 0, 0);
                acc[mf][nf] = __builtin_amdgcn_mfma_f32_16x16x32_f16(ah[mf], bl[nf], acc[mf][nf], 0, 0, 0);
                acc[mf][nf] = __builtin_amdgcn_mfma_f32_16x16x32_f16(al[mf], bh[nf], acc[mf][nf], 0, 0, 0);
            }
        }
#pragma unroll
        for (int nf = 0; nf < 4; ++nf) { bh[nf] = bh2[nf]; bl[nf] = bl2[nf]; }
    }

    int chunk = (nt & 3) * 2 + (wv & 1);        // 64-col chunk index, ascending n
#pragma unroll
    for (int mf = 0; mf < 4; ++mf) {
#pragma unroll
        for (int r = 0; r < 4; ++r) {
            float v = -__builtin_inff(); int idx = 0x7fffffff;
#pragma unroll
            for (int nf = 0; nf < 4; ++nf) {
                int n_way = n0w + ncol_w + nf * 16 + lc;
                float cv = acc[mf][nf][r];
                if (n_way < MS && cv > v) { v = cv; idx = n_way; }
            }
#pragma unroll
            for (int msk = 1; msk < 16; msk <<= 1) {
                float ov = __shfl_xor(v, msk);
                int oi = __shfl_xor(idx, msk);
                if (ov > v || (ov == v && oi < idx)) { v = ov; idx = oi; }
            }
            if (lc == 0) {
                int mrow = m0 + mrow_w + mf * 16 + lq * 4 + r;
                size_t o = ((size_t)(b * NWAY + w) * NCH + chunk) * MPAD + mrow;
                pmax[o] = v;
                pidx[o] = (unsigned short)(idx & 0xffff);
            }
        }
    }
}

// ================= FALLBACK PATH (ws too small) =================
__global__ void norm_support(const float* __restrict__ sup, float* __restrict__ snre) {
    int bid = blockIdx.x;
    int b = bid / 25, s = bid % 25;
    int w = s / KSHOT, shot = s % KSHOT;
    const float* src = sup + (size_t)bid * CC * HW;
    float* dst = snre + ((size_t)(b * NWAY + w)) * CC * MSP + shot * HW;
    __shared__ float inv[HW];
    int t = threadIdx.x;
    if (t < HW) {
        float ss = 0.f;
        for (int c = 0; c < CC; ++c) { float v = src[c * HW + t]; ss += v * v; }
        inv[t] = 1.f / (sqrtf(ss) + EPSN);
    }
    __syncthreads();
    for (int i = t; i < CC * HW; i += 256) {
        int c = i / HW, p = i % HW;
        dst[c * MSP + p] = src[i] * inv[p];
    }
    if (shot == KSHOT - 1) {
        float* padbase = snre + ((size_t)(b * NWAY + w)) * CC * MSP;
        for (int i = t; i < CC * (MSP - MS); i += 256) {
            int c = i / (MSP - MS), j = i % (MSP - MS);
            padbase[c * MSP + MS + j] = 0.f;
        }
    }
}

__global__ __launch_bounds__(256) void simkernel_fb(
        const float* __restrict__ qx, const float* __restrict__ snre,
        float* __restrict__ pmax, unsigned short* __restrict__ pidx) {
    __shared__ char lds_fb[49152];
    v8h* AHI = (v8h*)(lds_fb);
    v8h* ALO = (v8h*)(lds_fb + 8192);
    v8h* BHI = (v8h*)(lds_fb + 16384);
    v8h* BLO = (v8h*)(lds_fb + 32768);

    int bid = blockIdx.x;
    int mt = bid % 60; int t2 = bid / 60;
    int nt = t2 % 10;  int b = t2 / 10;
    int m0 = mt * 128;
    int w = nt >> 1;
    int n0w = (nt & 1) * 256;

    int tid = threadIdx.x;
    const float* Abase = qx + (size_t)b * QQ * CC * HW;
    const float* Bbase = snre + (size_t)(b * NWAY + w) * CC * MSP;

    int oct = tid & 3;
    int arow = tid >> 2;
    int aqi[2], ap[2];
#pragma unroll
    for (int pass = 0; pass < 2; ++pass) {
        int mg = m0 + arow + pass * 64;
        if (mg >= MTOT) mg = 0;
        aqi[pass] = mg / HW; ap[pass] = mg % HW;
    }

    v4f acc[4][8];
#pragma unroll
    for (int mf = 0; mf < 4; ++mf)
#pragma unroll
        for (int nf = 0; nf < 8; ++nf) acc[mf][nf] = (v4f)0.f;

    int lane = tid & 63;
    int wv = tid >> 6;
    int mrow_w = (wv >> 1) * 64;
    int ncol_w = (wv & 1) * 128;
    int lq = lane >> 4, lc = lane & 15;

    for (int ch = 0; ch < 20; ++ch) {
        int c0 = ch * 32 + oct * 8;
        __syncthreads();
#pragma unroll
        for (int pass = 0; pass < 2; ++pass) {
            const float* src = Abase + ((size_t)aqi[pass] * CC + c0) * HW + ap[pass];
            float x[8];
#pragma unroll
            for (int j = 0; j < 8; ++j) x[j] = src[j * HW];
            v8h hi, lo; splitv(x, hi, lo);
            int cell = (arow + pass * 64) * 4 + oct;
            AHI[cell] = hi; ALO[cell] = lo;
        }
#pragma unroll
        for (int pass = 0; pass < 4; ++pass) {
            int nrow = arow + pass * 64;
            const float* src = Bbase + (size_t)c0 * MSP + n0w + nrow;
            float x[8];
#pragma unroll
            for (int j = 0; j < 8; ++j) x[j] = src[j * MSP];
            v8h hi, lo; splitv(x, hi, lo);
            int cell = nrow * 4 + oct;
            BHI[cell] = hi; BLO[cell] = lo;
        }
        __syncthreads();

        v8h ahi[4], alo[4];
#pragma unroll
        for (int mf = 0; mf < 4; ++mf) {
            int idx = (mrow_w + mf * 16 + lc) * 4 + lq;
            ahi[mf] = AHI[idx]; alo[mf] = ALO[idx];
        }
#pragma unroll
        for (int nf = 0; nf < 8; ++nf) {
            int idx = (ncol_w + nf * 16 + lc) * 4 + lq;
            v8h bhi = BHI[idx], blo = BLO[idx];
#pragma unroll
            for (int mf = 0; mf < 4; ++mf) {
                acc[mf][nf] = __builtin_amdgcn_mfma_f32_16x16x32_f16(ahi[mf], bhi, acc[mf][nf], 0, 0, 0);
                acc[mf][nf] = __builtin_amdgcn_mfma_f32_16x16x32_f16(ahi[mf], blo, acc[mf][nf], 0, 0, 0);
                acc[mf][nf] = __builtin_amdgcn_mfma_f32_16x16x32_f16(alo[mf], bhi, acc[mf][nf], 0, 0, 0);
            }
        }
    }

    int chunkidx = (nt & 1) * 2 + (wv & 1);   // 128-col chunk of the way
#pragma unroll
    for (int mf = 0; mf < 4; ++mf) {
#pragma unroll
        for (int r = 0; r < 4; ++r) {
            float v = -__builtin_inff(); int idx = 0x7fffffff;
#pragma unroll
            for (int nf = 0; nf < 8; ++nf) {
                int n_way = n0w + ncol_w + nf * 16 + lc;
                float cv = acc[mf][nf][r];
                if (n_way < MS && cv > v) { v = cv; idx = n_way; }
            }
#pragma unroll
            for (int msk = 1; msk < 16; msk <<= 1) {
                float ov = __shfl_xor(v, msk);
                int oi = __shfl_xor(idx, msk);
                if (ov > v || (ov == v && oi < idx)) { v = ov; idx = oi; }
            }
            if (lc == 0) {
                int mrow = m0 + mrow_w + mf * 16 + lq * 4 + r;
                size_t ob = (size_t)(b * NWAY + w) * NCH * MPAD + mrow;
                int s_hi = (idx != 0x7fffffff) ? (idx >> 6) : -1;  // 64-col slot
#pragma unroll
                for (int sl2 = 0; sl2 < 2; ++sl2) {
                    int sl = chunkidx * 2 + sl2;
                    if (sl == s_hi) {
                        pmax[ob + (size_t)sl * MPAD] = v;
                        pidx[ob + (size_t)sl * MPAD] = (unsigned short)(idx & 0xffff);
                    } else {
                        pmax[ob + (size_t)sl * MPAD] = -__builtin_inff();
                        pidx[ob + (size_t)sl * MPAD] = 0xffffu;
                    }
                }
            }
        }
    }
}

// ------- finalize: combine chunks + top-2 diff + mutual mask + predict + NLL -----
__global__ __launch_bounds__(128) void finalize(
        const float* __restrict__ pmax, const unsigned short* __restrict__ pidx,
        const float* __restrict__ invq, const int* __restrict__ qy,
        float* __restrict__ out) {
    int bq = blockIdx.x;
    int b = bq / QQ, qi = bq % QQ;
    __shared__ float sm[NWAY][HW];
    __shared__ int   si[NWAY][HW];
    __shared__ float diffv[HW];
    __shared__ int   nearest[HW];
    __shared__ float maskv[HW];
    __shared__ float pred[NWAY];
    int t = threadIdx.x;
    if (t < HW) {
        float iq = invq[bq * HW + t];
        for (int w = 0; w < NWAY; ++w) {
            size_t base = ((size_t)(b * NWAY + w) * NCH) * MPAD + qi * HW + t;
            float best = -__builtin_inff(); int bi = 0x7fffffff;
            for (int c = 0; c < NCH; ++c) {
                float v = pmax[base + (size_t)c * MPAD];
                if (v > best) { best = v; bi = pidx[base + (size_t)c * MPAD]; }
            }
            sm[w][t] = best * iq;
            si[w][t] = bi;
        }
    }
    __syncthreads();
    if (t < HW) {
        float v1 = -INFINITY, v2 = -INFINITY;
        float bestv = -INFINITY; int bestslot = 0;
        for (int w = 0; w < NWAY; ++w) {
            float v = sm[w][t];
            if (v > v1) { v2 = v1; v1 = v; } else if (v > v2) { v2 = v; }
            if (v > bestv) { bestv = v; bestslot = w * MS + si[w][t]; }
        }
        diffv[t] = v1 - v2;
        nearest[t] = bestslot;
    }
    __syncthreads();
    if (t < HW) {
        int slot = nearest[t];
        float bv = (nearest[0] == slot) ? diffv[0] : 0.f;
        int bm = 0;
        for (int m = 1; m < HW; ++m) {
            float val = (nearest[m] == slot) ? diffv[m] : 0.f;
            if (val > bv) { bv = val; bm = m; }
        }
        maskv[t] = (bm == t) ? TEMPER : 0.f;
    }
    __syncthreads();
    if (t < NWAY) {
        float s = 0.f;
        for (int m = 0; m < HW; ++m) s += sm[t][m] * maskv[m];
        pred[t] = s;
    }
    __syncthreads();
    if (t == 0) {
        float mx = pred[0];
        for (int w = 1; w < NWAY; ++w) mx = fmaxf(mx, pred[w]);
        float se = 0.f;
        for (int w = 0; w < NWAY; ++w) se += expf(pred[w] - mx);
        float lse = mx + logf(se);
        int y = qy[bq];
        atomicAdd(out, -(pred[y] - lse) * (1.f / (BB * QQ)));
    }
}

extern "C" void kernel_launch(void* const* d_in, const int* in_sizes, int n_in,
                              void* d_out, int out_size, void* d_ws, size_t ws_size,
                              hipStream_t stream) {
    const float* sup = (const float*)d_in[0];   // support_xf (4,25,640,10,10) f32
    const float* qx  = (const float*)d_in[2];   // query_xf   (4,75,640,10,10) f32
    const int*   qy  = (const int*)d_in[3];     // query_y    (4,75) int32
    float* out = (float*)d_out;

    // header region (~7.5 MB)
    size_t pcount = (size_t)BB * NWAY * NCH * MPAD;     // 1,228,800
    float* pmax = (float*)d_ws;
    unsigned short* pidx = (unsigned short*)(pmax + pcount);
    float* invq = (float*)(pidx + pcount);
    float* invs = invq + (size_t)BB * MTOT;
    char*  big = (char*)(invs + (size_t)BB * 25 * HW);
    size_t header = (size_t)(big - (char*)d_ws);
    size_t needA = (size_t)BB * MPAD * CC * 2;          // 39.3 MB per array
    size_t needB = (size_t)BB * NWAY * MSP * CC * 2;    // 13.1 MB per array
    size_t need_fast = header + 2 * (needA + needB);

    hipLaunchKernelGGL(norms, dim3(BB * QQ + BB * 25), dim3(128), 0, stream,
                       qx, sup, invq, invs, out);

    if (ws_size >= need_fast) {
        _Float16* Ahi = (_Float16*)big;
        _Float16* Alo = Ahi + (size_t)BB * MPAD * CC;
        _Float16* Bhi = Alo + (size_t)BB * MPAD * CC;
        _Float16* Blo = Bhi + (size_t)BB * NWAY * MSP * CC;
        hipLaunchKernelGGL(prep_AB, dim3(BB * QQ * 10 + BB * 25 * 10), dim3(256), 0, stream,
                           qx, sup, invs, Ahi, Alo, Bhi, Blo);
        hipLaunchKernelGGL(simkernel, dim3(BB * 20 * 60), dim3(256), 0, stream,
                           Ahi, Alo, Bhi, Blo, pmax, pidx);
    } else {
        float* snre = (float*)big;   // 26.2 MB
        hipLaunchKernelGGL(norm_support, dim3(BB * 25), dim3(256), 0, stream, sup, snre);
        hipLaunchKernelGGL(simkernel_fb, dim3(BB * 10 * 60), dim3(256), 0, stream,
                           qx, snre, pmax, pidx);
    }
    hipLaunchKernelGGL(finalize, dim3(BB * QQ), dim3(128), 0, stream,
                       pmax, pidx, invq, qy, out);
}